// Round 14
// baseline (381.881 us; speedup 1.0000x reference)
//
#include <hip/hip_runtime.h>
#include <cmath>

typedef _Float16 h8  __attribute__((ext_vector_type(8)));
typedef _Float16 h4v __attribute__((ext_vector_type(4)));
typedef float    f4  __attribute__((ext_vector_type(4)));

#define NB  4096
#define NIN 4096
#define NNP 512
#define NP1 4096
#define NP2 8192
#define NH  2048

__device__ __forceinline__ void g2l(const void* g, void* l) {
  __builtin_amdgcn_global_load_lds((const __attribute__((address_space(1))) void*)g,
                                   (__attribute__((address_space(3))) void*)l, 16, 0, 0);
}

// ---------------- pack f32 -> f16 (vectorized) ----------------
__global__ __launch_bounds__(256) void k_pack_f16(const float* __restrict__ in,
                                                  _Float16* __restrict__ out, int n4) {
  int i = blockIdx.x * 256 + threadIdx.x;
  if (i >= n4) return;
  f4 v = ((const f4*)in)[i];
  h4v o;
  o[0] = (_Float16)v[0]; o[1] = (_Float16)v[1];
  o[2] = (_Float16)v[2]; o[3] = (_Float16)v[3];
  ((h4v*)out)[i] = o;
}

// ---------------- transpose pack: out[n][k] = in[k][n] * mask ----------------
template<bool MASK>
__global__ __launch_bounds__(256) void k_packT(const float* __restrict__ in,
                                               const int* __restrict__ comp,
                                               _Float16* __restrict__ out, int K, int N) {
  __shared__ float tile[64][65];
  const int n0 = blockIdx.x * 64, k0 = blockIdx.y * 64;
  const int tx = threadIdx.x & 63, ty = threadIdx.x >> 6;
#pragma unroll
  for (int r = 0; r < 16; ++r) {
    int kk = r * 4 + ty;
    float v = in[(long)(k0 + kk) * N + n0 + tx];
    if (MASK) v *= (float)comp[(long)(k0 + kk) * NNP + ((n0 + tx) >> 3)];
    tile[kk][tx] = v;
  }
  __syncthreads();
#pragma unroll
  for (int r = 0; r < 16; ++r) {
    int nn = r * 4 + ty;
    out[(long)(n0 + nn) * K + k0 + tx] = (_Float16)tile[tx][nn];
  }
}

// ---------------- Wc precompute: WcT[j][i] = sum_jj fc2w[i][16p+jj]*w1[16p+jj][j] ----------------
// One block per pathway p (i in [8p,8p+8)). Also emits per-pathway bias partials
// partialB[p][j] = sum_jj fc2b[16p+jj]*w1[16p+jj][j].
__global__ __launch_bounds__(256) void k_wc(const float* __restrict__ fc2w,
                                            const float* __restrict__ w1,
                                            const float* __restrict__ fc2b,
                                            _Float16* __restrict__ WcT,
                                            float* __restrict__ partialB) {
  const int p = blockIdx.x;
  const int tid = threadIdx.x;
  __shared__ float fs[8][16];
  __shared__ float bs[16];
  if (tid < 128) {
    int i = tid >> 4, jj = tid & 15;
    fs[i][jj] = fc2w[(long)(p * 8 + i) * NP2 + p * 16 + jj];
  }
  if (tid < 16) bs[tid] = fc2b[p * 16 + tid];
  __syncthreads();
#pragma unroll
  for (int c = 0; c < 8; ++c) {
    const int j = c * 256 + tid;
    float acc[8] = {0.f, 0.f, 0.f, 0.f, 0.f, 0.f, 0.f, 0.f};
    float bacc = 0.f;
#pragma unroll
    for (int jj = 0; jj < 16; ++jj) {
      const float w1v = w1[(long)(p * 16 + jj) * NH + j];
      bacc += bs[jj] * w1v;
#pragma unroll
      for (int i = 0; i < 8; ++i) acc[i] += fs[i][jj] * w1v;
    }
    h8 o;
#pragma unroll
    for (int i = 0; i < 8; ++i) o[i] = (_Float16)acc[i];
    *(h8*)&WcT[(long)j * NP1 + p * 8] = o;
    partialB[(long)p * NH + j] = bacc;
  }
}

// ---------------- bias_c[j] = sum_p partialB[p][j] + b1[j] ----------------
__global__ __launch_bounds__(256) void k_bias2(const float* __restrict__ partialB,
                                               const float* __restrict__ b1,
                                               float* __restrict__ biasc) {
  const int j = blockIdx.x * 256 + threadIdx.x;
  float a0 = 0.f, a1 = 0.f, a2 = 0.f, a3 = 0.f;
  for (int p = 0; p < NNP; p += 4) {
    a0 += partialB[(long)p * NH + j];
    a1 += partialB[(long)(p + 1) * NH + j];
    a2 += partialB[(long)(p + 2) * NH + j];
    a3 += partialB[(long)(p + 3) * NH + j];
  }
  biasc[j] = a0 + a1 + a2 + a3 + b1[j];
}

// ---------------- 256x256 fp16 GEMM, 16x16x32 frags, read-ahead pipelined 8-phase ----------------
// C = A[M,K] * BT[N,K]^T. EPI=0: C = acc + bias (fp16). EPI=1: fp16 split-K partial at ks*M*N.
// Structure verified R6/R13: zero-conflict swizzled LDS, race-free quadrant->half mapping,
// next-phase fragment read-ahead into alternate register sets, vmcnt(6) once per K-tile.
template<int EPI>
__global__ __launch_bounds__(512, 1) void k_gemm8(
    const _Float16* __restrict__ A, const _Float16* __restrict__ BT,
    const float* __restrict__ bias, _Float16* __restrict__ C,
    int M, int N, int K, int nbn, int ksplit) {
  extern __shared__ char smem[];
  // bijective XCD swizzle
  const int nwg = gridDim.x;
  const int q = nwg >> 3, r = nwg & 7;
  const int xcd = blockIdx.x & 7, idx = blockIdx.x >> 3;
  const int wg = (xcd < r ? xcd * (q + 1) : r * (q + 1) + (xcd - r) * q) + idx;
  const int tpk = nwg / ksplit;
  const int ks = wg / tpk;
  const int rem = wg - ks * tpk;
  const int bm = rem / nbn, bn = rem % nbn;
  const long m0 = (long)bm << 8, n0 = (long)bn << 8;
  const int Ks = K / ksplit;
  const int NT = Ks >> 6;              // BK=64, NT even

  const int tid = threadIdx.x;
  const int lane = tid & 63, w = tid >> 6;
  const int wm = w >> 2, wn = w & 3;
  const int lh = lane & 15, ls = lane >> 4;
  const int swz = (lh & 7) << 4;
  const int c0 = (ls * 16) ^ swz;
  const int c1 = (64 + ls * 16) ^ swz;
  const int arow = (wm * 64 + lh) * 128;           // + mh*16384 + m_*2048
  const int brow = 32768 + (wn * 32 + lh) * 128;   // + nh*16384 + n_*2048

  const long sKb = (long)K * 2;
  const int scb = (((tid & 7) ^ ((tid >> 3) & 7)) << 4);
  const char* Ag = (const char*)A + (m0 + (tid >> 3)) * sKb + (long)ks * Ks * 2 + scb;
  const char* Bg = (const char*)BT + (n0 + (tid >> 3)) * sKb + (long)ks * Ks * 2 + scb;
  const long h64 = 64 * sKb, h128 = 128 * sKb;
  const int lw = w << 10;

#define STAGE_A(buf, hh, kb) do { \
    const char* s_ = Ag + (hh) * h128 + (kb); \
    char* d_ = smem + (buf) * 65536 + (hh) * 16384 + lw; \
    g2l(s_, d_); g2l(s_ + h64, d_ + 8192); } while (0)
#define STAGE_B(buf, hh, kb) do { \
    const char* s_ = Bg + (hh) * h128 + (kb); \
    char* d_ = smem + (buf) * 65536 + 32768 + (hh) * 16384 + lw; \
    g2l(s_, d_); g2l(s_ + h64, d_ + 8192); } while (0)
#define READ_A(dst, buf, mh) do { \
    _Pragma("unroll") for (int m_ = 0; m_ < 4; ++m_) { \
      dst[m_][0] = *(const h8*)(smem + (buf) * 65536 + (mh) * 16384 + arow + m_ * 2048 + c0); \
      dst[m_][1] = *(const h8*)(smem + (buf) * 65536 + (mh) * 16384 + arow + m_ * 2048 + c1); } } while (0)
#define READ_B(dst, buf, nh) do { \
    _Pragma("unroll") for (int n_ = 0; n_ < 2; ++n_) { \
      dst[n_][0] = *(const h8*)(smem + (buf) * 65536 + (nh) * 16384 + brow + n_ * 2048 + c0); \
      dst[n_][1] = *(const h8*)(smem + (buf) * 65536 + (nh) * 16384 + brow + n_ * 2048 + c1); } } while (0)
#define MM(mh, nh, aset, bset) do { \
    _Pragma("unroll") for (int kq_ = 0; kq_ < 2; ++kq_) \
    _Pragma("unroll") for (int m_ = 0; m_ < 4; ++m_) \
    _Pragma("unroll") for (int n_ = 0; n_ < 2; ++n_) \
      acc[mh][nh][m_][n_] = __builtin_amdgcn_mfma_f32_16x16x32_f16(aset[m_][kq_], bset[n_][kq_], acc[mh][nh][m_][n_], 0, 0, 0); } while (0)
#define BAR() asm volatile("s_barrier" ::: "memory")
#define VM6() asm volatile("s_waitcnt vmcnt(6)" ::: "memory")
#define VM8() asm volatile("s_waitcnt vmcnt(8)" ::: "memory")
#define PR1() __builtin_amdgcn_s_setprio(1)
#define PR0() __builtin_amdgcn_s_setprio(0)

  f4 acc[2][2][4][2] = {};   // [mh][nh][m][n]
  h8 afA[4][2], afB[4][2];
  h8 bfA[2][2], bfB[2][2];

  auto kc = [&](int t) -> long { return (long)(t < NT ? t : NT - 1) << 7; };

  // prologue
  STAGE_A(0, 0, kc(0)); STAGE_B(0, 0, kc(0)); STAGE_B(0, 1, kc(0)); STAGE_A(0, 1, kc(0));
  STAGE_A(1, 0, kc(1)); STAGE_B(1, 0, kc(1)); STAGE_B(1, 1, kc(1)); STAGE_A(1, 1, kc(1));
  VM8();
  BAR();
  READ_A(afA, 0, 0);
  READ_B(bfA, 0, 0);

  for (int t2 = 0; t2 < NT; t2 += 2) {
    // ===== even tile t2 (buf0) =====
    BAR();
    READ_B(bfB, 0, 1);
    STAGE_A(0, 0, kc(t2 + 2));
    PR1(); MM(0, 0, afA, bfA); PR0();
    BAR();
    READ_A(afB, 0, 1);
    STAGE_B(0, 1, kc(t2 + 2));
    PR1(); MM(0, 1, afA, bfB); PR0();
    BAR();
    STAGE_A(0, 1, kc(t2 + 2));
    VM6();
    READ_A(afA, 1, 0);
    PR1(); MM(1, 1, afB, bfB); PR0();
    BAR();
    READ_B(bfB, 1, 0);
    STAGE_B(0, 0, kc(t2 + 2));
    PR1(); MM(1, 0, afB, bfA); PR0();
    // ===== odd tile t2+1 (buf1) =====
    BAR();
    READ_B(bfA, 1, 1);
    STAGE_A(1, 0, kc(t2 + 3));
    PR1(); MM(0, 0, afA, bfB); PR0();
    BAR();
    READ_A(afB, 1, 1);
    STAGE_B(1, 1, kc(t2 + 3));
    PR1(); MM(0, 1, afA, bfA); PR0();
    BAR();
    STAGE_A(1, 1, kc(t2 + 3));
    VM6();
    READ_A(afA, 0, 0);
    PR1(); MM(1, 1, afB, bfA); PR0();
    BAR();
    READ_B(bfA, 0, 0);
    STAGE_B(1, 0, kc(t2 + 3));
    PR1(); MM(1, 0, afB, bfB); PR0();
  }

  // epilogue: 16x16 C/D layout col=lane&15, row=(lane>>4)*4+j
  _Float16* dst = (EPI == 1) ? (C + (long)ks * M * N) : C;
#pragma unroll
  for (int mh = 0; mh < 2; ++mh)
#pragma unroll
  for (int m = 0; m < 4; ++m) {
    const long r0 = m0 + mh * 128 + wm * 64 + m * 16 + ls * 4;
#pragma unroll
    for (int nh = 0; nh < 2; ++nh)
#pragma unroll
    for (int n = 0; n < 2; ++n) {
      const long c = n0 + nh * 128 + wn * 32 + n * 16 + lh;
      const float bv = (EPI == 0) ? bias[c] : 0.f;
#pragma unroll
      for (int j = 0; j < 4; ++j)
        dst[(r0 + j) * N + c] = (_Float16)(acc[mh][nh][m][n][j] + bv);
    }
  }
#undef STAGE_A
#undef STAGE_B
#undef READ_A
#undef READ_B
#undef MM
#undef BAR
#undef VM6
#undef VM8
#undef PR1
#undef PR0
}

// ---------------- fused splitK-reduce + bias + relu + GEMM4 + sigmoid ----------------
__global__ __launch_bounds__(256) void k_logits(const _Float16* __restrict__ part,
                                                const float* __restrict__ b1,
                                                const float* __restrict__ w2,
                                                const float* __restrict__ b2,
                                                float* __restrict__ logits,
                                                float* __restrict__ hazards) {
  const int lane = threadIdx.x & 63;
  const int b = blockIdx.x * 4 + (threadIdx.x >> 6);
  const long off2 = (long)NB * NH;
  f4 acc = {0.f, 0.f, 0.f, 0.f};
  const _Float16* p0 = part + (long)b * NH;
  const _Float16* p1 = p0 + off2;
#pragma unroll
  for (int c4 = 0; c4 < 4; ++c4) {
    const int k0 = c4 * 512 + lane * 8;
    h8 a = *(const h8*)&p0[k0];
    h8 bb = *(const h8*)&p1[k0];
    f4 bva = *(const f4*)&b1[k0];
    f4 bvb = *(const f4*)&b1[k0 + 4];
#pragma unroll
    for (int u = 0; u < 8; ++u) {
      const float bias = (u < 4) ? bva[u] : bvb[u - 4];
      const float hv = fmaxf((float)a[u] + (float)bb[u] + bias, 0.f);
      acc += hv * *(const f4*)&w2[(long)(k0 + u) * 4];
    }
  }
#pragma unroll
  for (int off = 32; off > 0; off >>= 1) {
#pragma unroll
    for (int u = 0; u < 4; ++u) acc[u] += __shfl_xor(acc[u], off, 64);
  }
  if (lane == 0) {
    f4 lg = acc + *(const f4*)b2;
    ((f4*)logits)[b] = lg;
    f4 hz;
#pragma unroll
    for (int u = 0; u < 4; ++u) hz[u] = 1.f / (1.f + expf(-lg[u]));
    ((f4*)hazards)[b] = hz;
  }
}

// ---------------- cumprod along batch + first-occurrence argmax ----------------
__global__ __launch_bounds__(256) void k_final(const float* __restrict__ logits,
                                               const float* __restrict__ hazards,
                                               float* __restrict__ S,
                                               float* __restrict__ yhat) {
  const int c = blockIdx.x;
  const int t = threadIdx.x;
  __shared__ float pl[256];
  __shared__ float mv[256];
  __shared__ int   mi[256];
  float prod = 1.f;
  float best = -1e30f; int bi = 0;
  for (int i = 0; i < 16; ++i) {
    const int b = t * 16 + i;
    prod *= (1.f - hazards[b * 4 + c]);
    const float lg = logits[b * 4 + c];
    if (lg > best) { best = lg; bi = b; }
  }
  pl[t] = prod; mv[t] = best; mi[t] = bi;
  __syncthreads();
  for (int off = 1; off < 256; off <<= 1) {
    float cur  = pl[t];
    float prev = (t >= off) ? pl[t - off] : 1.f;
    __syncthreads();
    pl[t] = cur * prev;
    __syncthreads();
  }
  float s = (t == 0) ? 1.f : pl[t - 1];
  for (int i = 0; i < 16; ++i) {
    const int b = t * 16 + i;
    s *= (1.f - hazards[b * 4 + c]);
    S[b * 4 + c] = s;
  }
  for (int off = 128; off > 0; off >>= 1) {
    if (t < off) {
      float ov = mv[t + off]; int oi = mi[t + off];
      if (ov > mv[t] || (ov == mv[t] && oi < mi[t])) { mv[t] = ov; mi[t] = oi; }
    }
    __syncthreads();
  }
  if (t == 0) yhat[c] = (float)mi[0];
}

extern "C" void kernel_launch(void* const* d_in, const int* in_sizes, int n_in,
                              void* d_out, int out_size, void* d_ws, size_t ws_size,
                              hipStream_t stream) {
  (void)in_sizes; (void)n_in; (void)out_size; (void)ws_size;
  const float* x    = (const float*)d_in[0];
  const float* fc1w = (const float*)d_in[1];
  const float* fc1b = (const float*)d_in[2];
  const float* fc2w = (const float*)d_in[3];
  const float* fc2b = (const float*)d_in[4];
  const float* w1   = (const float*)d_in[5];
  const float* b1   = (const float*)d_in[6];
  const float* w2   = (const float*)d_in[7];
  const float* b2   = (const float*)d_in[8];
  const int*   comp = (const int*)d_in[9];

  char* ws = (char*)d_ws;
  const size_t MB = 1024ull * 1024ull;
  // region plan (peak ~116MB):
  //   [0,32M)      xh
  //   [32M,64M)    w1mT   -> dead after GEMM1 -> part (fp16 2x16MB)
  //   [64M,96M)    out1h  -> dead after GEMM3' -> logits
  //   [96M,112M)   WcT (fp16 [2048][4096])
  //   [112M,116M)  partialB (f32 [512][2048])
  //   [116M,+8K)   bias_c (f32 [2048])
  _Float16* xh     = (_Float16*)(ws + 0);
  _Float16* w1mT   = (_Float16*)(ws + 32 * MB);
  _Float16* out1h  = (_Float16*)(ws + 64 * MB);
  _Float16* WcT    = (_Float16*)(ws + 96 * MB);
  float*    partB  = (float*)(ws + 112 * MB);
  float*    biasc  = (float*)(ws + 116 * MB);
  _Float16* part   = (_Float16*)(ws + 32 * MB);
  float*    logits = (float*)(ws + 64 * MB);
  float*    outF   = (float*)d_out;

  hipFuncSetAttribute(reinterpret_cast<const void*>(k_gemm8<0>),
                      hipFuncAttributeMaxDynamicSharedMemorySize, 131072);
  hipFuncSetAttribute(reinterpret_cast<const void*>(k_gemm8<1>),
                      hipFuncAttributeMaxDynamicSharedMemorySize, 131072);

  // 1) pack x -> fp16
  k_pack_f16<<<(NB * NIN / 4) / 256, 256, 0, stream>>>(x, xh, NB * NIN / 4);
  // 2) pack (fc1_w * mask1)^T -> fp16 [P1][IN]
  k_packT<true><<<dim3(NP1 / 64, NIN / 64), 256, 0, stream>>>(fc1w, comp, w1mT, NIN, NP1);
  // 3) WcT = (block-diag fc2w @ w1)^T fp16 ; per-pathway bias partials
  k_wc<<<NNP, 256, 0, stream>>>(fc2w, w1, fc2b, WcT, partB);
  // 4) bias_c = fc2b @ w1 + b1
  k_bias2<<<NH / 256, 256, 0, stream>>>(partB, b1, biasc);
  // 5) GEMM1: out1 = x @ fc1w_masked + fc1_b
  k_gemm8<0><<<(NB / 256) * (NP1 / 256), 512, 131072, stream>>>(
      xh, w1mT, fc1b, out1h, NB, NP1, NIN, NP1 / 256, 1);
  // 6) GEMM3': fp16 partials = out1 @ Wc (split-K=2, K=4096) -> overlays dead w1mT
  k_gemm8<1><<<(NB / 256) * (NH / 256) * 2, 512, 131072, stream>>>(
      out1h, WcT, nullptr, part, NB, NH, NP1, NH / 256, 2);
  // 7) fused: h = relu(p0+p1+bias_c); logits = h@w2+b2; hazards = sigmoid
  k_logits<<<NB / 4, 256, 0, stream>>>(part, biasc, w2, b2, logits, outF);
  // 8) S and Y_hat
  k_final<<<4, 256, 0, stream>>>(logits, outF, outF + NB * 4, outF + 2 * NB * 4);
}

// Round 15
// 271.209 us; speedup vs baseline: 1.4081x; 1.4081x over previous
//
#include <hip/hip_runtime.h>
#include <cmath>

typedef _Float16 h8  __attribute__((ext_vector_type(8)));
typedef _Float16 h4v __attribute__((ext_vector_type(4)));
typedef float    f4  __attribute__((ext_vector_type(4)));

#define NB  4096
#define NIN 4096
#define NNP 512
#define NP1 4096
#define NP2 8192
#define NH  2048

__device__ __forceinline__ void g2l(const void* g, void* l) {
  __builtin_amdgcn_global_load_lds((const __attribute__((address_space(1))) void*)g,
                                   (__attribute__((address_space(3))) void*)l, 16, 0, 0);
}

// ---------------- pack f32 -> f16 (vectorized) ----------------
__global__ __launch_bounds__(256) void k_pack_f16(const float* __restrict__ in,
                                                  _Float16* __restrict__ out, int n4) {
  int i = blockIdx.x * 256 + threadIdx.x;
  if (i >= n4) return;
  f4 v = ((const f4*)in)[i];
  h4v o;
  o[0] = (_Float16)v[0]; o[1] = (_Float16)v[1];
  o[2] = (_Float16)v[2]; o[3] = (_Float16)v[3];
  ((h4v*)out)[i] = o;
}

// ---------------- transpose pack: out[n][k] = in[k][n] * mask ----------------
template<bool MASK>
__global__ __launch_bounds__(256) void k_packT(const float* __restrict__ in,
                                               const int* __restrict__ comp,
                                               _Float16* __restrict__ out, int K, int N) {
  __shared__ float tile[64][65];
  const int n0 = blockIdx.x * 64, k0 = blockIdx.y * 64;
  const int tx = threadIdx.x & 63, ty = threadIdx.x >> 6;
#pragma unroll
  for (int r = 0; r < 16; ++r) {
    int kk = r * 4 + ty;
    float v = in[(long)(k0 + kk) * N + n0 + tx];
    if (MASK) v *= (float)comp[(long)(k0 + kk) * NNP + ((n0 + tx) >> 3)];
    tile[kk][tx] = v;
  }
  __syncthreads();
#pragma unroll
  for (int r = 0; r < 16; ++r) {
    int nn = r * 4 + ty;
    out[(long)(n0 + nn) * K + k0 + tx] = (_Float16)tile[tx][nn];
  }
}

// ---------------- Wc precompute, coalesced (transpose-tiled) ----------------
// Block = 64 j-cols x 8 pathways. WcT[j][p*8+i] = sum_jj fc2w[p*8+i][p*16+jj] * w1[p*16+jj][j].
// w1 reads coalesced (each element exactly once across grid); WcT written as coalesced
// 128B row segments via an LDS transpose tile ([64][9] h8 pad -> conflict-free slots).
// Also emits bpart[p_tile][j] = sum over this p-tile of fc2b[..]*w1[..][j].
__global__ __launch_bounds__(256) void k_wc3(const float* __restrict__ fc2w,
                                             const float* __restrict__ w1,
                                             const float* __restrict__ fc2b,
                                             _Float16* __restrict__ WcT,
                                             float* __restrict__ bpart) {
  const int j0 = blockIdx.x * 64;      // 32 j-tiles
  const int p0 = blockIdx.y * 8;       // 64 p-tiles
  const int tid = threadIdx.x;
  const int tx = tid & 63, ty = tid >> 6;

  __shared__ float fs[8][8][16];       // fc2w sub-blocks
  __shared__ float bs[8][16];          // fc2b slices
  __shared__ h8    tile[64][9];        // j x pathway (padded: slot=(row+chunk)%8 bijection)
  __shared__ float bl[4][64];          // bias partial reduce over ty

  // stage fc2w blocks (1024 values) + fc2b (128 values)
#pragma unroll
  for (int k = 0; k < 4; ++k) {
    int t = tid + k * 256;
    int pl = t >> 7, i = (t >> 4) & 7, jj = t & 15;
    fs[pl][i][jj] = fc2w[(long)((p0 + pl) * 8 + i) * NP2 + (p0 + pl) * 16 + jj];
  }
  if (tid < 128) {
    int pl = tid >> 4, jj = tid & 15;
    bs[pl][jj] = fc2b[(p0 + pl) * 16 + jj];
  }
  __syncthreads();

  float tbacc = 0.f;
#pragma unroll
  for (int s = 0; s < 2; ++s) {
    const int pl = ty + s * 4;
    float acc[8] = {0.f, 0.f, 0.f, 0.f, 0.f, 0.f, 0.f, 0.f};
#pragma unroll
    for (int jj = 0; jj < 16; ++jj) {
      const float w1v = w1[(long)((p0 + pl) * 16 + jj) * NH + j0 + tx];
      tbacc += bs[pl][jj] * w1v;
#pragma unroll
      for (int i = 0; i < 8; ++i) acc[i] += fs[pl][i][jj] * w1v;
    }
    h8 o;
#pragma unroll
    for (int i = 0; i < 8; ++i) o[i] = (_Float16)acc[i];
    tile[tx][pl] = o;
  }
  bl[ty][tx] = tbacc;
  __syncthreads();

  // coalesced WcT writes: 512 16B chunks, 2 per thread
#pragma unroll
  for (int k = 0; k < 2; ++k) {
    int qc = tid + k * 256;
    int jrow = qc >> 3, pi = qc & 7;
    *(h8*)&WcT[(long)(j0 + jrow) * NP1 + (p0 + pi) * 8] = tile[jrow][pi];
  }
  if (tid < 64)
    bpart[(long)blockIdx.y * NH + j0 + tid] = bl[0][tid] + bl[1][tid] + bl[2][tid] + bl[3][tid];
}

// ---------------- bias_c[j] = sum_q bpart[q][j] + b1[j] ----------------
__global__ __launch_bounds__(256) void k_bias2(const float* __restrict__ bpart,
                                               const float* __restrict__ b1,
                                               float* __restrict__ biasc) {
  const int j = blockIdx.x * 256 + threadIdx.x;
  float a0 = 0.f, a1 = 0.f, a2 = 0.f, a3 = 0.f;
#pragma unroll
  for (int q = 0; q < 64; q += 8) {
    a0 += bpart[(long)q * NH + j]       + bpart[(long)(q + 4) * NH + j];
    a1 += bpart[(long)(q + 1) * NH + j] + bpart[(long)(q + 5) * NH + j];
    a2 += bpart[(long)(q + 2) * NH + j] + bpart[(long)(q + 6) * NH + j];
    a3 += bpart[(long)(q + 3) * NH + j] + bpart[(long)(q + 7) * NH + j];
  }
  biasc[j] = a0 + a1 + a2 + a3 + b1[j];
}

// ---------------- 256x256 fp16 GEMM, 16x16x32 frags, read-ahead pipelined 8-phase ----------------
// C = A[M,K] * BT[N,K]^T. EPI=0: C = acc + bias (fp16). EPI=1: fp16 split-K partial at ks*M*N.
// Structure verified R6/R13: zero-conflict swizzled LDS, race-free quadrant->half mapping,
// next-phase fragment read-ahead into alternate register sets, vmcnt(6) once per K-tile.
template<int EPI>
__global__ __launch_bounds__(512, 1) void k_gemm8(
    const _Float16* __restrict__ A, const _Float16* __restrict__ BT,
    const float* __restrict__ bias, _Float16* __restrict__ C,
    int M, int N, int K, int nbn, int ksplit) {
  extern __shared__ char smem[];
  // bijective XCD swizzle
  const int nwg = gridDim.x;
  const int q = nwg >> 3, r = nwg & 7;
  const int xcd = blockIdx.x & 7, idx = blockIdx.x >> 3;
  const int wg = (xcd < r ? xcd * (q + 1) : r * (q + 1) + (xcd - r) * q) + idx;
  const int tpk = nwg / ksplit;
  const int ks = wg / tpk;
  const int rem = wg - ks * tpk;
  const int bm = rem / nbn, bn = rem % nbn;
  const long m0 = (long)bm << 8, n0 = (long)bn << 8;
  const int Ks = K / ksplit;
  const int NT = Ks >> 6;              // BK=64, NT even

  const int tid = threadIdx.x;
  const int lane = tid & 63, w = tid >> 6;
  const int wm = w >> 2, wn = w & 3;
  const int lh = lane & 15, ls = lane >> 4;
  const int swz = (lh & 7) << 4;
  const int c0 = (ls * 16) ^ swz;
  const int c1 = (64 + ls * 16) ^ swz;
  const int arow = (wm * 64 + lh) * 128;           // + mh*16384 + m_*2048
  const int brow = 32768 + (wn * 32 + lh) * 128;   // + nh*16384 + n_*2048

  const long sKb = (long)K * 2;
  const int scb = (((tid & 7) ^ ((tid >> 3) & 7)) << 4);
  const char* Ag = (const char*)A + (m0 + (tid >> 3)) * sKb + (long)ks * Ks * 2 + scb;
  const char* Bg = (const char*)BT + (n0 + (tid >> 3)) * sKb + (long)ks * Ks * 2 + scb;
  const long h64 = 64 * sKb, h128 = 128 * sKb;
  const int lw = w << 10;

#define STAGE_A(buf, hh, kb) do { \
    const char* s_ = Ag + (hh) * h128 + (kb); \
    char* d_ = smem + (buf) * 65536 + (hh) * 16384 + lw; \
    g2l(s_, d_); g2l(s_ + h64, d_ + 8192); } while (0)
#define STAGE_B(buf, hh, kb) do { \
    const char* s_ = Bg + (hh) * h128 + (kb); \
    char* d_ = smem + (buf) * 65536 + 32768 + (hh) * 16384 + lw; \
    g2l(s_, d_); g2l(s_ + h64, d_ + 8192); } while (0)
#define READ_A(dst, buf, mh) do { \
    _Pragma("unroll") for (int m_ = 0; m_ < 4; ++m_) { \
      dst[m_][0] = *(const h8*)(smem + (buf) * 65536 + (mh) * 16384 + arow + m_ * 2048 + c0); \
      dst[m_][1] = *(const h8*)(smem + (buf) * 65536 + (mh) * 16384 + arow + m_ * 2048 + c1); } } while (0)
#define READ_B(dst, buf, nh) do { \
    _Pragma("unroll") for (int n_ = 0; n_ < 2; ++n_) { \
      dst[n_][0] = *(const h8*)(smem + (buf) * 65536 + (nh) * 16384 + brow + n_ * 2048 + c0); \
      dst[n_][1] = *(const h8*)(smem + (buf) * 65536 + (nh) * 16384 + brow + n_ * 2048 + c1); } } while (0)
#define MM(mh, nh, aset, bset) do { \
    _Pragma("unroll") for (int kq_ = 0; kq_ < 2; ++kq_) \
    _Pragma("unroll") for (int m_ = 0; m_ < 4; ++m_) \
    _Pragma("unroll") for (int n_ = 0; n_ < 2; ++n_) \
      acc[mh][nh][m_][n_] = __builtin_amdgcn_mfma_f32_16x16x32_f16(aset[m_][kq_], bset[n_][kq_], acc[mh][nh][m_][n_], 0, 0, 0); } while (0)
#define BAR() asm volatile("s_barrier" ::: "memory")
#define VM6() asm volatile("s_waitcnt vmcnt(6)" ::: "memory")
#define VM8() asm volatile("s_waitcnt vmcnt(8)" ::: "memory")
#define PR1() __builtin_amdgcn_s_setprio(1)
#define PR0() __builtin_amdgcn_s_setprio(0)

  f4 acc[2][2][4][2] = {};   // [mh][nh][m][n]
  h8 afA[4][2], afB[4][2];
  h8 bfA[2][2], bfB[2][2];

  auto kc = [&](int t) -> long { return (long)(t < NT ? t : NT - 1) << 7; };

  // prologue
  STAGE_A(0, 0, kc(0)); STAGE_B(0, 0, kc(0)); STAGE_B(0, 1, kc(0)); STAGE_A(0, 1, kc(0));
  STAGE_A(1, 0, kc(1)); STAGE_B(1, 0, kc(1)); STAGE_B(1, 1, kc(1)); STAGE_A(1, 1, kc(1));
  VM8();
  BAR();
  READ_A(afA, 0, 0);
  READ_B(bfA, 0, 0);

  for (int t2 = 0; t2 < NT; t2 += 2) {
    // ===== even tile t2 (buf0) =====
    BAR();
    READ_B(bfB, 0, 1);
    STAGE_A(0, 0, kc(t2 + 2));
    PR1(); MM(0, 0, afA, bfA); PR0();
    BAR();
    READ_A(afB, 0, 1);
    STAGE_B(0, 1, kc(t2 + 2));
    PR1(); MM(0, 1, afA, bfB); PR0();
    BAR();
    STAGE_A(0, 1, kc(t2 + 2));
    VM6();
    READ_A(afA, 1, 0);
    PR1(); MM(1, 1, afB, bfB); PR0();
    BAR();
    READ_B(bfB, 1, 0);
    STAGE_B(0, 0, kc(t2 + 2));
    PR1(); MM(1, 0, afB, bfA); PR0();
    // ===== odd tile t2+1 (buf1) =====
    BAR();
    READ_B(bfA, 1, 1);
    STAGE_A(1, 0, kc(t2 + 3));
    PR1(); MM(0, 0, afA, bfB); PR0();
    BAR();
    READ_A(afB, 1, 1);
    STAGE_B(1, 1, kc(t2 + 3));
    PR1(); MM(0, 1, afA, bfA); PR0();
    BAR();
    STAGE_A(1, 1, kc(t2 + 3));
    VM6();
    READ_A(afA, 0, 0);
    PR1(); MM(1, 1, afB, bfA); PR0();
    BAR();
    READ_B(bfA, 0, 0);
    STAGE_B(1, 0, kc(t2 + 3));
    PR1(); MM(1, 0, afB, bfB); PR0();
  }

  // epilogue: 16x16 C/D layout col=lane&15, row=(lane>>4)*4+j
  _Float16* dst = (EPI == 1) ? (C + (long)ks * M * N) : C;
#pragma unroll
  for (int mh = 0; mh < 2; ++mh)
#pragma unroll
  for (int m = 0; m < 4; ++m) {
    const long r0 = m0 + mh * 128 + wm * 64 + m * 16 + ls * 4;
#pragma unroll
    for (int nh = 0; nh < 2; ++nh)
#pragma unroll
    for (int n = 0; n < 2; ++n) {
      const long c = n0 + nh * 128 + wn * 32 + n * 16 + lh;
      const float bv = (EPI == 0) ? bias[c] : 0.f;
#pragma unroll
      for (int j = 0; j < 4; ++j)
        dst[(r0 + j) * N + c] = (_Float16)(acc[mh][nh][m][n][j] + bv);
    }
  }
#undef STAGE_A
#undef STAGE_B
#undef READ_A
#undef READ_B
#undef MM
#undef BAR
#undef VM6
#undef VM8
#undef PR1
#undef PR0
}

// ---------------- fused splitK-reduce + bias + relu + GEMM4 + sigmoid ----------------
__global__ __launch_bounds__(256) void k_logits(const _Float16* __restrict__ part,
                                                const float* __restrict__ b1,
                                                const float* __restrict__ w2,
                                                const float* __restrict__ b2,
                                                float* __restrict__ logits,
                                                float* __restrict__ hazards) {
  const int lane = threadIdx.x & 63;
  const int b = blockIdx.x * 4 + (threadIdx.x >> 6);
  const long off2 = (long)NB * NH;
  f4 acc = {0.f, 0.f, 0.f, 0.f};
  const _Float16* p0 = part + (long)b * NH;
  const _Float16* p1 = p0 + off2;
#pragma unroll
  for (int c4 = 0; c4 < 4; ++c4) {
    const int k0 = c4 * 512 + lane * 8;
    h8 a = *(const h8*)&p0[k0];
    h8 bb = *(const h8*)&p1[k0];
    f4 bva = *(const f4*)&b1[k0];
    f4 bvb = *(const f4*)&b1[k0 + 4];
#pragma unroll
    for (int u = 0; u < 8; ++u) {
      const float bias = (u < 4) ? bva[u] : bvb[u - 4];
      const float hv = fmaxf((float)a[u] + (float)bb[u] + bias, 0.f);
      acc += hv * *(const f4*)&w2[(long)(k0 + u) * 4];
    }
  }
#pragma unroll
  for (int off = 32; off > 0; off >>= 1) {
#pragma unroll
    for (int u = 0; u < 4; ++u) acc[u] += __shfl_xor(acc[u], off, 64);
  }
  if (lane == 0) {
    f4 lg = acc + *(const f4*)b2;
    ((f4*)logits)[b] = lg;
    f4 hz;
#pragma unroll
    for (int u = 0; u < 4; ++u) hz[u] = 1.f / (1.f + expf(-lg[u]));
    ((f4*)hazards)[b] = hz;
  }
}

// ---------------- cumprod along batch + first-occurrence argmax ----------------
__global__ __launch_bounds__(256) void k_final(const float* __restrict__ logits,
                                               const float* __restrict__ hazards,
                                               float* __restrict__ S,
                                               float* __restrict__ yhat) {
  const int c = blockIdx.x;
  const int t = threadIdx.x;
  __shared__ float pl[256];
  __shared__ float mv[256];
  __shared__ int   mi[256];
  float prod = 1.f;
  float best = -1e30f; int bi = 0;
  for (int i = 0; i < 16; ++i) {
    const int b = t * 16 + i;
    prod *= (1.f - hazards[b * 4 + c]);
    const float lg = logits[b * 4 + c];
    if (lg > best) { best = lg; bi = b; }
  }
  pl[t] = prod; mv[t] = best; mi[t] = bi;
  __syncthreads();
  for (int off = 1; off < 256; off <<= 1) {
    float cur  = pl[t];
    float prev = (t >= off) ? pl[t - off] : 1.f;
    __syncthreads();
    pl[t] = cur * prev;
    __syncthreads();
  }
  float s = (t == 0) ? 1.f : pl[t - 1];
  for (int i = 0; i < 16; ++i) {
    const int b = t * 16 + i;
    s *= (1.f - hazards[b * 4 + c]);
    S[b * 4 + c] = s;
  }
  for (int off = 128; off > 0; off >>= 1) {
    if (t < off) {
      float ov = mv[t + off]; int oi = mi[t + off];
      if (ov > mv[t] || (ov == mv[t] && oi < mi[t])) { mv[t] = ov; mi[t] = oi; }
    }
    __syncthreads();
  }
  if (t == 0) yhat[c] = (float)mi[0];
}

extern "C" void kernel_launch(void* const* d_in, const int* in_sizes, int n_in,
                              void* d_out, int out_size, void* d_ws, size_t ws_size,
                              hipStream_t stream) {
  (void)in_sizes; (void)n_in; (void)out_size; (void)ws_size;
  const float* x    = (const float*)d_in[0];
  const float* fc1w = (const float*)d_in[1];
  const float* fc1b = (const float*)d_in[2];
  const float* fc2w = (const float*)d_in[3];
  const float* fc2b = (const float*)d_in[4];
  const float* w1   = (const float*)d_in[5];
  const float* b1   = (const float*)d_in[6];
  const float* w2   = (const float*)d_in[7];
  const float* b2   = (const float*)d_in[8];
  const int*   comp = (const int*)d_in[9];

  char* ws = (char*)d_ws;
  const size_t MB = 1024ull * 1024ull;
  // region plan (peak ~117MB):
  //   [0,32M)      xh
  //   [32M,64M)    w1mT   -> dead after GEMM1 -> part (fp16 2x16MB)
  //   [64M,96M)    out1h  -> dead after GEMM3' -> logits
  //   [96M,112M)   WcT (fp16 [2048][4096])
  //   [112M,113M)  bpart (f32 [64][2048] = 512KB)
  //   [116M,+8K)   bias_c (f32 [2048])
  _Float16* xh     = (_Float16*)(ws + 0);
  _Float16* w1mT   = (_Float16*)(ws + 32 * MB);
  _Float16* out1h  = (_Float16*)(ws + 64 * MB);
  _Float16* WcT    = (_Float16*)(ws + 96 * MB);
  float*    bpart  = (float*)(ws + 112 * MB);
  float*    biasc  = (float*)(ws + 116 * MB);
  _Float16* part   = (_Float16*)(ws + 32 * MB);
  float*    logits = (float*)(ws + 64 * MB);
  float*    outF   = (float*)d_out;

  hipFuncSetAttribute(reinterpret_cast<const void*>(k_gemm8<0>),
                      hipFuncAttributeMaxDynamicSharedMemorySize, 131072);
  hipFuncSetAttribute(reinterpret_cast<const void*>(k_gemm8<1>),
                      hipFuncAttributeMaxDynamicSharedMemorySize, 131072);

  // 1) pack x -> fp16
  k_pack_f16<<<(NB * NIN / 4) / 256, 256, 0, stream>>>(x, xh, NB * NIN / 4);
  // 2) pack (fc1_w * mask1)^T -> fp16 [P1][IN]
  k_packT<true><<<dim3(NP1 / 64, NIN / 64), 256, 0, stream>>>(fc1w, comp, w1mT, NIN, NP1);
  // 3) WcT = (block-diag fc2w @ w1)^T fp16, coalesced; bias partials per p-tile
  k_wc3<<<dim3(NH / 64, NNP / 8), 256, 0, stream>>>(fc2w, w1, fc2b, WcT, bpart);
  // 4) bias_c = fc2b @ w1 + b1
  k_bias2<<<NH / 256, 256, 0, stream>>>(bpart, b1, biasc);
  // 5) GEMM1: out1 = x @ fc1w_masked + fc1_b
  k_gemm8<0><<<(NB / 256) * (NP1 / 256), 512, 131072, stream>>>(
      xh, w1mT, fc1b, out1h, NB, NP1, NIN, NP1 / 256, 1);
  // 6) GEMM3': fp16 partials = out1 @ Wc (split-K=2, K=4096) -> overlays dead w1mT
  k_gemm8<1><<<(NB / 256) * (NH / 256) * 2, 512, 131072, stream>>>(
      out1h, WcT, nullptr, part, NB, NH, NP1, NH / 256, 2);
  // 7) fused: h = relu(p0+p1+bias_c); logits = h@w2+b2; hazards = sigmoid
  k_logits<<<NB / 4, 256, 0, stream>>>(part, biasc, w2, b2, logits, outF);
  // 8) S and Y_hat
  k_final<<<4, 256, 0, stream>>>(logits, outF, outF + NB * 4, outF + 2 * NB * 4);
}